// Round 1
// baseline (1936.964 us; speedup 1.0000x reference)
//
#include <hip/hip_runtime.h>

// Eikonal 3D — 288 Jacobi-parallel Godunov sweeps on a 96^3 grid.
// u0 = BIG except source (48,48,48)=0; each sweep: upwind-min neighbors per
// axis, sorted (lo,mid,hi), 1D/2D/3D candidates, monotone min update, pin src.
// Ping-pong: A = d_out, B = d_ws. 288 steps (even) -> final lands in d_out.

#define N   96
#define N2  (96 * 96)
#define N3  (96 * 96 * 96)
#define BIGV 1e5f
#define SRC_IDX (48 * N2 + 48 * N + 48)

__global__ __launch_bounds__(256) void eik_init(float* __restrict__ u) {
    int idx = blockIdx.x * 256 + threadIdx.x;
    u[idx] = (idx == SRC_IDX) ? 0.0f : BIGV;
}

__global__ __launch_bounds__(256) void eik_step(const float* __restrict__ u,
                                                const float* __restrict__ f,
                                                float* __restrict__ un) {
    int idx = blockIdx.x * 256 + threadIdx.x;
    // idx = i*N2 + j*N + k  (k contiguous -> coalesced)
    int k = idx % N;
    int t = idx / N;
    int j = t % N;
    int i = t / N;

    float uc = u[idx];

    float xm = (i > 0)     ? u[idx - N2] : BIGV;
    float xp = (i < N - 1) ? u[idx + N2] : BIGV;
    float ym = (j > 0)     ? u[idx - N]  : BIGV;
    float yp = (j < N - 1) ? u[idx + N]  : BIGV;
    float zm = (k > 0)     ? u[idx - 1]  : BIGV;
    float zp = (k < N - 1) ? u[idx + 1]  : BIGV;

    float a = fminf(xm, xp);
    float b = fminf(ym, yp);
    float c = fminf(zm, zp);

    float lo  = fminf(fminf(a, b), c);
    float hi  = fmaxf(fmaxf(a, b), c);
    float mid = a + b + c - lo - hi;          // match JAX left-assoc order

    float fh = f[idx];                        // H = 1.0

    // 1D candidate
    float u1 = lo + fh;

    // 2D candidate (guarded)
    float dlm = lo - mid;
    float d2  = 2.0f * fh * fh - dlm * dlm;
    float u2  = (d2 > 0.0f) ? 0.5f * (lo + mid + sqrtf(d2)) : BIGV;

    // 3D candidate (guarded)
    float s  = lo + mid + hi;
    float q  = lo * lo + mid * mid + hi * hi - fh * fh;
    float d3 = s * s - 3.0f * q;
    float u3 = (d3 > 0.0f) ? (s + sqrtf(d3)) / 3.0f : BIGV;

    float cand = (u1 <= mid) ? u1 : ((u2 <= hi) ? u2 : u3);
    float unv  = fminf(uc, cand);             // monotone (causality)

    if (idx == SRC_IDX) unv = 0.0f;           // pin source
    un[idx] = unv;
}

extern "C" void kernel_launch(void* const* d_in, const int* in_sizes, int n_in,
                              void* d_out, int out_size, void* d_ws, size_t ws_size,
                              hipStream_t stream) {
    const float* f = (const float*)d_in[0];
    float* A = (float*)d_out;   // even-iteration source / final result
    float* B = (float*)d_ws;    // odd-iteration buffer (>= 3.4 MB scratch)

    const int nblk = N3 / 256;  // 3456, exact

    eik_init<<<nblk, 256, 0, stream>>>(A);

    for (int it = 0; it < 288; ++it) {
        const float* src = (it & 1) ? B : A;
        float*       dst = (it & 1) ? A : B;
        eik_step<<<nblk, 256, 0, stream>>>(src, f, dst);
    }
    // it=287 writes A == d_out
}